// Round 17
// baseline (139.254 us; speedup 1.0000x reference)
//
#include <hip/hip_runtime.h>
#include <cstddef>
#include <cstdint>

#define NB 8
#define CIN 256
#define LL 1024
#define DKC 512
#define DVC 256
#define XPSTRIDE 295936  // 34*34*256

typedef short short8 __attribute__((ext_vector_type(8)));
typedef float f32x4 __attribute__((ext_vector_type(4)));

typedef __attribute__((address_space(1))) const unsigned int gas_u32;
typedef __attribute__((address_space(3))) unsigned int las_u32;

__device__ __forceinline__ unsigned short f2bf(float f) {
  unsigned int u = __float_as_uint(f);
  u += 0x7fffu + ((u >> 16) & 1u);
  return (unsigned short)(u >> 16);
}
__device__ __forceinline__ float bf2f(unsigned short u) {
  return __uint_as_float(((unsigned int)u) << 16);
}

// ---------------- merged prep: xpad_interior + xpad_border + weight prep --
// blocks [0,128): xpad interior; [128,1184): border zeros; [1184,5056): weights
__global__ __launch_bounds__(256) void prep_all(
    const float* __restrict__ x, const float* __restrict__ wconv,
    const float* __restrict__ wqkv, const float* __restrict__ wout,
    const float* __restrict__ krh, const float* __restrict__ krw,
    unsigned short* __restrict__ xTp, unsigned short* __restrict__ wtap,
    unsigned short* __restrict__ wqbf, unsigned short* __restrict__ woutbf,
    unsigned short* __restrict__ relTh, unsigned short* __restrict__ relTw) {
  __shared__ float tile[64][65];
  const int bx = blockIdx.x;
  const int tid = threadIdx.x;
  if (bx < 128) {
    // ---- xpad interior: x [b][c][1024] fp32 -> xTp [b][34][34][c] bf16
    const int st = bx & 15;
    const int b = bx >> 4;
    const int s0 = st * 64;
    const int h0 = st * 2;
    for (int cc = 0; cc < 4; ++cc) {
      const int c0 = cc * 64;
      {
        const int row = tid >> 2;
        const int j0 = (tid & 3) * 16;
#pragma unroll
        for (int k = 0; k < 4; ++k)
          *(float4*)&tile[row][j0 + k * 4] =
              *(const float4*)(x + ((size_t)(b * CIN + c0 + row)) * LL + s0 + j0 + k * 4);
      }
      __syncthreads();
      {
        const int sl = tid >> 2;
        const int cb = (tid & 3) * 16;
        unsigned short buf[16];
#pragma unroll
        for (int m = 0; m < 16; ++m) buf[m] = f2bf(tile[cb + m][sl]);
        const int hp = h0 + (sl >> 5) + 1;
        const int wp = (sl & 31) + 1;
        unsigned short* dst = xTp + (size_t)b * XPSTRIDE + (hp * 34 + wp) * 256 + c0 + cb;
        *(uint4*)dst = *(uint4*)&buf[0];
        *(uint4*)(dst + 8) = *(uint4*)&buf[8];
      }
      __syncthreads();
    }
  } else if (bx < 1184) {
    // ---- xpad border zeros
    const int idx = (bx - 128) * 256 + tid;
    const int b = idx / 33792;
    const int rem = idx - b * 33792;
    const int pos = rem >> 8, c = rem & 255;
    int hp, wp;
    if (pos < 34) { hp = 0; wp = pos; }
    else if (pos < 68) { hp = 33; wp = pos - 34; }
    else if (pos < 100) { hp = pos - 68 + 1; wp = 0; }
    else { hp = pos - 100 + 1; wp = 33; }
    xTp[(size_t)b * XPSTRIDE + (hp * 34 + wp) * 256 + c] = 0;
  } else {
    // ---- weight/rel prep (fp32 -> bf16, relayout)
    const int idx = (bx - 1184) * 256 + tid;
    if (idx < 589824) {
      // coalesced READ of wconv; scattered write to wtap (fire-and-forget).
      // bijection: j = rem*9 + tap  ->  wtap[tap*65536 + rem]
      const int j = idx;
      const int rem = j / 9;
      const int tap = j - rem * 9;
      wtap[tap * 65536 + rem] = f2bf(wconv[j]);
    } else if (idx < 917504) {
      const int j = idx - 589824;
      const int o = j >> 8;
      const float sc = (o < DKC) ? 0.125f * 1.44269504088896f : 1.0f;
      wqbf[j] = f2bf(wqkv[j] * sc);
    } else if (idx < 983040) {
      const int j = idx - 917504;
      woutbf[j] = f2bf(wout[j]);
    } else {
      const int j = idx - 983040;
      const int tbl = j >> 12;
      const int rest = j & 4095;
      const int m = rest >> 6, c = rest & 63;
      const float* src = tbl ? krw : krh;
      unsigned short* dst = tbl ? relTw : relTh;
      const float v = (m < 63) ? src[c * 63 + m] : 0.f;
      dst[m * 64 + c] = f2bf(v);
    }
  }
}

// ---------------- merged qkv + conv, 1-D grid, XCD-safe role split -------
// lin < 512: conv (long poles, dispatched first); lin >= 512: qkv.
// BATCH -> XCD alignment (T1 mechanism): b = lin&7 in both roles, so XCD x
// (block lin%8 == x, and 512%8==0 keeps qkv congruent) touches ONLY batch
// x's xTp slice (592 KB, L2-resident) across conv's 9 tap re-reads and
// qkv's read. Per-CU co-resident blocks (lin+256k) also share the batch.
// Staging via global_load_lds with pre-swizzled source (r13-r15 pattern).
__global__ __launch_bounds__(256) void qkvconv_mfma(
    const unsigned short* __restrict__ xTp, const unsigned short* __restrict__ wqbf,
    const unsigned short* __restrict__ wtap, unsigned short* __restrict__ qbf,
    unsigned short* __restrict__ kbf, unsigned short* __restrict__ vbf,
    float* __restrict__ out) {
  __shared__ __align__(16) char smem[32768];
  const int tid = threadIdx.x;
  const int lane = tid & 63, w = tid >> 6;
  const int n16 = lane & 15, quad = lane >> 4;
  const int lin = blockIdx.x;
  const int trow = tid >> 3;
  const int lr = lane >> 3;            // 0..7
  const int lg = lane & 7;
  const int gsw = (lg ^ lr) * 8;       // pre-swizzled granule (u16 offset)

  if (lin < 512) {
    // ================= conv (implicit GEMM, BK=64, async dbuf) ==========
    const int b = lin & 7;             // batch == XCD
    const int rest = lin >> 3;         // 0..63
    const int ot = rest & 3;
    const int st = rest >> 2;          // 0..15
    const int s0 = st * 64;
    const int h0 = st * 2;
    unsigned short* asb = (unsigned short*)smem;             // 2x[64][64]
    unsigned short* bsb = (unsigned short*)(smem + 16384);   // 2x[64][64]
    const unsigned short* xb = xTp + (size_t)b * XPSTRIDE;
    const unsigned short* wbase = wtap + (size_t)(ot * 64) * 256;

    f32x4 acc[4];
#pragma unroll
    for (int nt = 0; nt < 4; ++nt) acc[nt] = (f32x4){0.f, 0.f, 0.f, 0.f};

    auto issue = [&](int it, int bufi) {
      const int tap = it >> 2;
      const int c0 = (it & 3) * 64;
      const int dh = tap / 3 - 1;
      const int dw = tap - (tap / 3) * 3 - 1;
      const unsigned short* wt = wbase + (size_t)tap * 65536;
      unsigned short* ad = asb + bufi * 4096 + w * 512;
      unsigned short* bd = bsb + bufi * 4096 + w * 512;
      const unsigned short* asrc = wt + (size_t)trow * 256 + c0 + gsw;
      __builtin_amdgcn_global_load_lds((gas_u32*)asrc, (las_u32*)ad, 16, 0, 0);
      __builtin_amdgcn_global_load_lds((gas_u32*)(asrc + 32 * 256), (las_u32*)(ad + 2048), 16, 0, 0);
      const int wp = trow + dw + 1;      // trow 0..31
      const unsigned short* bsrc = xb + (size_t)((h0 + dh + 1) * 34 + wp) * 256 + c0 + gsw;
      __builtin_amdgcn_global_load_lds((gas_u32*)bsrc, (las_u32*)bd, 16, 0, 0);
      __builtin_amdgcn_global_load_lds((gas_u32*)(bsrc + 34 * 256), (las_u32*)(bd + 2048), 16, 0, 0);
    };
    issue(0, 0);
    for (int it = 0; it < 36; ++it) {
      __syncthreads();                  // tile it ready (vmcnt0 drained)
      if (it < 35) issue(it + 1, (it + 1) & 1);  // async into other buffer
      const unsigned short* ab = asb + (it & 1) * 4096;
      const unsigned short* bb = bsb + (it & 1) * 4096;
      short8 a0 = *(const short8*)&ab[(w * 16 + n16) * 64 + ((quad ^ (n16 & 7)) * 8)];
      short8 a1 = *(const short8*)&ab[(w * 16 + n16) * 64 + (((quad + 4) ^ (n16 & 7)) * 8)];
#pragma unroll
      for (int nt = 0; nt < 4; ++nt) {
        short8 b0 = *(const short8*)&bb[(nt * 16 + n16) * 64 + ((quad ^ (n16 & 7)) * 8)];
        short8 b1 = *(const short8*)&bb[(nt * 16 + n16) * 64 + (((quad + 4) ^ (n16 & 7)) * 8)];
        acc[nt] = __builtin_amdgcn_mfma_f32_16x16x32_bf16(a0, b0, acc[nt], 0, 0, 0);
        acc[nt] = __builtin_amdgcn_mfma_f32_16x16x32_bf16(a1, b1, acc[nt], 0, 0, 0);
      }
    }
#pragma unroll
    for (int nt = 0; nt < 4; ++nt)
#pragma unroll
      for (int reg = 0; reg < 4; ++reg)
        out[((size_t)b * 512 + ot * 64 + w * 16 + quad * 4 + reg) * LL + s0 + nt * 16 + n16] =
            acc[nt][reg];
  } else {
    // ================= qkv projection (async dbuf, 1 barrier/iter) ======
    const int l2 = lin - 512;        // 0..2559; l2%8 == lin%8 (512%8==0)
    const int b = l2 & 7;            // batch == XCD
    const int rest = l2 >> 3;        // 0..319 = 20*16
    const int ot = rest % 20;
    const int st = rest / 20;        // 0..15
    const int o0 = ot * 64;
    const int s0 = st * 64;
    const int h0 = st * 2;
    unsigned short* asb = (unsigned short*)smem;             // 2x[64][64]
    unsigned short* bsb = (unsigned short*)(smem + 16384);   // 2x[64][64]
    float (*trans)[65] = (float(*)[65])smem;  // overlays after final reads

    const unsigned short* xb = xTp + (size_t)b * XPSTRIDE;
    const unsigned short* wt = wqbf + (size_t)o0 * 256;

    f32x4 acc[4];
#pragma unroll
    for (int nt = 0; nt < 4; ++nt) acc[nt] = (f32x4){0.f, 0.f, 0.f, 0.f};

    auto issue = [&](int kc, int bufi) {
      const int c0 = kc * 64;
      unsigned short* ad = asb + bufi * 4096 + w * 512;
      unsigned short* bd = bsb + bufi * 4096 + w * 512;
      const unsigned short* asrc = wt + (size_t)trow * 256 + c0 + gsw;
      __builtin_amdgcn_global_load_lds((gas_u32*)asrc, (las_u32*)ad, 16, 0, 0);
      __builtin_amdgcn_global_load_lds((gas_u32*)(asrc + 32 * 256), (las_u32*)(ad + 2048), 16, 0, 0);
      const int wpos = trow + 1;         // trow 0..31
      const unsigned short* bsrc = xb + (size_t)((h0 + 1) * 34 + wpos) * 256 + c0 + gsw;
      __builtin_amdgcn_global_load_lds((gas_u32*)bsrc, (las_u32*)bd, 16, 0, 0);
      __builtin_amdgcn_global_load_lds((gas_u32*)(bsrc + 34 * 256), (las_u32*)(bd + 2048), 16, 0, 0);
    };
    issue(0, 0);
#pragma unroll
    for (int kc = 0; kc < 4; ++kc) {
      __syncthreads();                  // tile kc ready (vmcnt0 drained)
      if (kc < 3) issue(kc + 1, (kc + 1) & 1);
      const unsigned short* as = asb + (kc & 1) * 4096;
      const unsigned short* bs = bsb + (kc & 1) * 4096;
      short8 a0 = *(const short8*)&as[(w * 16 + n16) * 64 + ((quad ^ (n16 & 7)) * 8)];
      short8 a1 = *(const short8*)&as[(w * 16 + n16) * 64 + (((quad + 4) ^ (n16 & 7)) * 8)];
#pragma unroll
      for (int nt = 0; nt < 4; ++nt) {
        short8 b0 = *(const short8*)&bs[(nt * 16 + n16) * 64 + ((quad ^ (n16 & 7)) * 8)];
        short8 b1 = *(const short8*)&bs[(nt * 16 + n16) * 64 + (((quad + 4) ^ (n16 & 7)) * 8)];
        acc[nt] = __builtin_amdgcn_mfma_f32_16x16x32_bf16(a0, b0, acc[nt], 0, 0, 0);
        acc[nt] = __builtin_amdgcn_mfma_f32_16x16x32_bf16(a1, b1, acc[nt], 0, 0, 0);
      }
    }
    __syncthreads();
#pragma unroll
    for (int nt = 0; nt < 4; ++nt)
#pragma unroll
      for (int reg = 0; reg < 4; ++reg)
        trans[w * 16 + quad * 4 + reg][nt * 16 + n16] = acc[nt][reg];
    __syncthreads();
    const int sl = tid >> 2;
    const int cseg = (tid & 3) * 16;
    unsigned short buf[16];
    if (ot < 16) {
#pragma unroll
      for (int m = 0; m < 16; ++m) buf[m] = f2bf(trans[cseg + m][sl]);
      unsigned short* dst;
      int head;
      if (ot < 8) { dst = qbf; head = ot; }
      else { dst = kbf; head = ot - 8; }
      const size_t base = (((size_t)(b * 8 + head)) * LL + s0 + sl) * 64 + cseg;
      *(uint4*)(dst + base) = *(uint4*)&buf[0];
      *(uint4*)(dst + base + 8) = *(uint4*)&buf[8];
    } else {
#pragma unroll
      for (int m = 0; m < 16; ++m) buf[m] = f2bf(trans[sl][cseg + m]);
      unsigned short* dst = vbf + ((size_t)b * DVC + (ot - 16) * 64 + sl) * LL + s0 + cseg;
      *(uint4*)dst = *(uint4*)&buf[0];
      *(uint4*)(dst + 8) = *(uint4*)&buf[8];
    }
  }
}

// ---------------- MFMA flash attention: swapped QK^T, in-register P ------
// round-9 structure, K/V staging via global_load_lds (width 16) with
// pre-swizzled global source (r13, verified). blk%8 == head n -> each XCD
// streams exactly one head's K/V (1.57 MB, L2-resident) -- already optimal.
__global__ __launch_bounds__(256, 4) void attn_kernel(
    const unsigned short* __restrict__ qbf, const unsigned short* __restrict__ kbf,
    const unsigned short* __restrict__ vbf, const unsigned short* __restrict__ relTh,
    const unsigned short* __restrict__ relTw, unsigned short* __restrict__ abf) {
  __shared__ __align__(16) char smem[32768];
  unsigned short* ks = (unsigned short*)smem;              // 2x[64][64] swizzled
  unsigned short* vs = (unsigned short*)(smem + 16384);    // 2x[32][64] swizzled
  unsigned short* rwtT = (unsigned short*)(smem + 24576);  // [64 m][64 q] swizzled
  unsigned short* ps = (unsigned short*)(smem + 8192);     // transient rh tile (= ks buf1)
  float* obuf = (float*)smem;                              // [64][33] fp32 overlay

  const int tid = threadIdx.x;
  const int lane = tid & 63, w = tid >> 6;
  const int n16 = lane & 15, quad = lane >> 4;
  const int blk = blockIdx.x;
  const int bn = blk & 63, qb = blk >> 6;
  const int n = bn & 7, b = bn >> 3;
  const int s0 = qb * 64;
  const int aa = 2 * qb + (w >> 1);
  const int pb = (w & 1) * 16;

  const unsigned short* qbase = qbf + ((size_t)(b * 8 + n)) * LL * 64;
  const unsigned short* kbase = kbf + ((size_t)(b * 8 + n)) * LL * 64;
  const unsigned short* vbase = vbf + ((size_t)(b * 8 + n)) * 32 * LL;

  // staging geometry: lane l of wave w fetches row 8w+(l>>3), granule l&7
  const int lr = lane >> 3;                       // 0..7
  const int lg = lane & 7;
  const int wkey = (lr & 3) | ((w & 1) << 2);     // == key(8w+lr) == key(+32)
  const int gsw = (lg ^ wkey) * 8;                // pre-swizzled granule (u16)
  const int krow0 = w * 8 + lr;                   // 0..31
  // read keys (lane-constant): kb rows krb+..., vb rows ct*16+n16
  const int krb = (n16 >> 2) * 8 + (n16 & 3);
  const int kk = (n16 & 3) | (((n16 >> 2) & 1) << 2);
  const int vk = (n16 & 3) | (((n16 >> 3) & 1) << 2);
  const int qcol = w * 16 + n16;

  auto issue_tile = [&](int t0, int bufi) {
    unsigned short* kd = ks + bufi * 4096 + w * 512;
    unsigned short* vd = vs + bufi * 2048 + w * 512;
    const unsigned short* ksrc = kbase + (size_t)(t0 + krow0) * 64 + gsw;
    __builtin_amdgcn_global_load_lds((gas_u32*)ksrc, (las_u32*)kd, 16, 0, 0);
    __builtin_amdgcn_global_load_lds((gas_u32*)(ksrc + 32 * 64), (las_u32*)(kd + 2048), 16, 0, 0);
    __builtin_amdgcn_global_load_lds((gas_u32*)(vbase + (size_t)krow0 * LL + t0 + gsw),
                                     (las_u32*)vd, 16, 0, 0);
  };

  // stage tile 0 into buffer 0 (async; drains at the prologue barrier)
  issue_tile(0, 0);

  // ---- prologue: rel tables via MFMA; rw -> transposed LDS, rh transient --
  {
    const int sT = (pb + n16) * 32 + aa;
    short8 ra0 = *(const short8*)(qbase + (size_t)sT * 64 + quad * 8);
    short8 ra1 = *(const short8*)(qbase + (size_t)sT * 64 + 32 + quad * 8);
#pragma unroll
    for (int tbl = 0; tbl < 2; ++tbl) {
      const unsigned short* rel = tbl ? relTh : relTw;
      f32x4 acc[4];
#pragma unroll
      for (int mt = 0; mt < 4; ++mt) acc[mt] = (f32x4){0.f, 0.f, 0.f, 0.f};
#pragma unroll
      for (int mt = 0; mt < 4; ++mt) {
        short8 b0 = *(const short8*)(rel + (mt * 16 + n16) * 64 + quad * 8);
        short8 b1 = *(const short8*)(rel + (mt * 16 + n16) * 64 + 32 + quad * 8);
        acc[mt] = __builtin_amdgcn_mfma_f32_16x16x32_bf16(ra0, b0, acc[mt], 0, 0, 0);
        acc[mt] = __builtin_amdgcn_mfma_f32_16x16x32_bf16(ra1, b1, acc[mt], 0, 0, 0);
      }
      if (tbl == 0) {
#pragma unroll
        for (int mt = 0; mt < 4; ++mt)
#pragma unroll
          for (int reg = 0; reg < 4; ++reg)
            rwtT[(mt * 16 + n16) * 64 +
                 ((w * 16 + quad * 4 + reg) ^ ((n16 & 7) * 8))] = f2bf(acc[mt][reg]);
      } else {
#pragma unroll
        for (int mt = 0; mt < 4; ++mt)
#pragma unroll
          for (int reg = 0; reg < 4; ++reg)
            ps[(w * 16 + quad * 4 + reg) * 64 + mt * 16 + n16] = f2bf(acc[mt][reg]);
      }
    }
  }
  short8 qf0 = *(const short8*)(qbase + (size_t)(s0 + w * 16 + n16) * 64 + quad * 8);
  short8 qf1 = *(const short8*)(qbase + (size_t)(s0 + w * 16 + n16) * 64 + 32 + quad * 8);
  __syncthreads();  // tile-0 loads drained (vmcnt0); rel tables visible
  // hoist rh bias into 8 regs: q = qcol, k%32 = quad*8 + c1*4 + reg
  float rhreg[2][4];
#pragma unroll
  for (int c1 = 0; c1 < 2; ++c1)
#pragma unroll
    for (int reg = 0; reg < 4; ++reg)
      rhreg[c1][reg] =
          bf2f(ps[qcol * 64 + quad * 8 + c1 * 4 + reg + 31 - pb - n16]);
  __syncthreads();  // ps (= ks buf1) reads done before iter0 loads buf1

  float lacc[4] = {0.f, 0.f, 0.f, 0.f};
  f32x4 oacc[2];
  oacc[0] = (f32x4){0.f, 0.f, 0.f, 0.f};
  oacc[1] = (f32x4){0.f, 0.f, 0.f, 0.f};

  int cur = 0;
  for (int kt64 = 0; kt64 < 16; ++kt64) {
    const int t0 = kt64 * 64;
    __syncthreads();  // buf[cur] ready; all waves done reading buf[cur^1]
    if (kt64 < 15) issue_tile(t0 + 64, cur ^ 1);  // async into the other buffer
    const unsigned short* ksb = ks + cur * 4096;
    const unsigned short* vsb = vs + cur * 2048;

    // swapped QK^T with permuted K rows: sacc[c][reg] =
    //   S[q=qcol][k = t0 + (c>>1)*32 + (c&1)*4 + quad*8 + reg]
    f32x4 sacc[4];
#pragma unroll
    for (int c = 0; c < 4; ++c) sacc[c] = (f32x4){0.f, 0.f, 0.f, 0.f};
#pragma unroll
    for (int c = 0; c < 4; ++c) {
      const int ro = (krb + (c & 1) * 4 + (c >> 1) * 32) * 64;
      short8 kb0 = *(const short8*)&ksb[ro + ((quad ^ kk) * 8)];
      short8 kb1 = *(const short8*)&ksb[ro + (((quad + 4) ^ kk) * 8)];
      sacc[c] = __builtin_amdgcn_mfma_f32_16x16x32_bf16(kb0, qf0, sacc[c], 0, 0, 0);
      sacc[c] = __builtin_amdgcn_mfma_f32_16x16x32_bf16(kb1, qf1, sacc[c], 0, 0, 0);
    }
    // rw bias: one u16 per 32-k half for this lane's q row
    float rww[2];
#pragma unroll
    for (int h = 0; h < 2; ++h) {
      const int mw = (t0 >> 5) + h - aa + 31;
      rww[h] = bf2f(rwtT[mw * 64 + (qcol ^ ((mw & 7) * 8))]);
    }
    // P = exp2(s + rw + rh), packed to bf16 pairs entirely in-register
    unsigned int pkw[2][4];
#pragma unroll
    for (int c = 0; c < 4; ++c) {
      float e[4];
#pragma unroll
      for (int reg = 0; reg < 4; ++reg) {
        e[reg] = __builtin_amdgcn_exp2f(sacc[c][reg] + rww[c >> 1] + rhreg[c & 1][reg]);
        lacc[reg] += e[reg];
      }
      unsigned int p0, p1;
      asm("v_cvt_pk_bf16_f32 %0, %1, %2" : "=v"(p0) : "v"(e[0]), "v"(e[1]));
      asm("v_cvt_pk_bf16_f32 %0, %1, %2" : "=v"(p1) : "v"(e[2]), "v"(e[3]));
      pkw[c >> 1][(c & 1) * 2] = p0;
      pkw[c >> 1][(c & 1) * 2 + 1] = p1;
    }
    // PV: pa is lane-local A-fragment, V from LDS
#pragma unroll
    for (int kt = 0; kt < 2; ++kt) {
      uint4 pw;
      pw.x = pkw[kt][0]; pw.y = pkw[kt][1]; pw.z = pkw[kt][2]; pw.w = pkw[kt][3];
      short8 pa = *(short8*)&pw;
#pragma unroll
      for (int ct = 0; ct < 2; ++ct) {
        short8 vb = *(const short8*)&vsb[(ct * 16 + n16) * 64 + (((quad + 4 * kt) ^ vk) * 8)];
        oacc[ct] = __builtin_amdgcn_mfma_f32_16x16x32_bf16(pa, vb, oacc[ct], 0, 0, 0);
      }
    }
    cur ^= 1;
  }
  // row-sum: lane holds partial for q=qcol; reduce across quads, then
  // redistribute 1/l to the O layout rows (quad*4+reg)
  float lsum = (lacc[0] + lacc[1]) + (lacc[2] + lacc[3]);
  lsum += __shfl_xor(lsum, 16);
  lsum += __shfl_xor(lsum, 32);
  const float linv_own = 1.0f / lsum;
  float linv[4];
#pragma unroll
  for (int reg = 0; reg < 4; ++reg)
    linv[reg] = __shfl(linv_own, (lane & 48) | (quad * 4 + reg));
  __syncthreads();
#pragma unroll
  for (int ct = 0; ct < 2; ++ct)
#pragma unroll
    for (int reg = 0; reg < 4; ++reg)
      obuf[(w * 16 + quad * 4 + reg) * 33 + ct * 16 + n16] = oacc[ct][reg] * linv[reg];
  __syncthreads();
  {
    const int row = tid >> 2;
    const int cseg = (tid & 3) * 8;
    unsigned short buf8[8];
#pragma unroll
    for (int m = 0; m < 8; ++m) buf8[m] = f2bf(obuf[row * 33 + cseg + m]);
    *(uint4*)(abf + (((size_t)b * LL) + s0 + row) * 256 + n * 32 + cseg) = *(uint4*)&buf8[0];
  }
}

// ---------------- output projection: async dbuf, batch->XCD 1-D grid -----
// b = lin&7 so XCD x reads only batch x's abf slice (4.2 MB ~ L2).
__global__ __launch_bounds__(256) void proj_mfma(
    const unsigned short* __restrict__ abf, const unsigned short* __restrict__ woutbf,
    float* __restrict__ out) {
  __shared__ __align__(16) char smem[32768];
  unsigned short* asb = (unsigned short*)smem;             // 2x[64][64]
  unsigned short* bsb = (unsigned short*)(smem + 16384);   // 2x[64][64]
  const int tid = threadIdx.x;
  const int lane = tid & 63, w = tid >> 6;
  const int n16 = lane & 15, quad = lane >> 4;
  const int lin = blockIdx.x;
  const int b = lin & 7;               // batch == XCD
  const int rest = lin >> 3;           // 0..63
  const int ot = rest & 3;
  const int st = rest >> 2;            // 0..15
  const int o0 = ot * 64;
  const int s0 = st * 64;
  const int trow = tid >> 3;
  const int lr = lane >> 3;
  const int lg = lane & 7;
  const int gsw = (lg ^ lr) * 8;       // pre-swizzled granule

  const unsigned short* ab = abf + ((size_t)b * LL + s0) * 256;
  const unsigned short* wt = woutbf + (size_t)o0 * 256;

  f32x4 acc[4];
#pragma unroll
  for (int nt = 0; nt < 4; ++nt) acc[nt] = (f32x4){0.f, 0.f, 0.f, 0.f};

  auto issue = [&](int kc, int bufi) {
    const int c0 = kc * 64;
    unsigned short* ad = asb + bufi * 4096 + w * 512;
    unsigned short* bd = bsb + bufi * 4096 + w * 512;
    const unsigned short* asrc = wt + (size_t)trow * 256 + c0 + gsw;
    __builtin_amdgcn_global_load_lds((gas_u32*)asrc, (las_u32*)ad, 16, 0, 0);
    __builtin_amdgcn_global_load_lds((gas_u32*)(asrc + 32 * 256), (las_u32*)(ad + 2048), 16, 0, 0);
    const unsigned short* bsrc = ab + (size_t)trow * 256 + c0 + gsw;
    __builtin_amdgcn_global_load_lds((gas_u32*)bsrc, (las_u32*)bd, 16, 0, 0);
    __builtin_amdgcn_global_load_lds((gas_u32*)(bsrc + 32 * 256), (las_u32*)(bd + 2048), 16, 0, 0);
  };
  issue(0, 0);
#pragma unroll
  for (int kc = 0; kc < 4; ++kc) {
    __syncthreads();                  // tile kc ready (vmcnt0 drained)
    if (kc < 3) issue(kc + 1, (kc + 1) & 1);
    const unsigned short* as = asb + (kc & 1) * 4096;
    const unsigned short* bs = bsb + (kc & 1) * 4096;
    short8 a0 = *(const short8*)&as[(w * 16 + n16) * 64 + ((quad ^ (n16 & 7)) * 8)];
    short8 a1 = *(const short8*)&as[(w * 16 + n16) * 64 + (((quad + 4) ^ (n16 & 7)) * 8)];
#pragma unroll
    for (int nt = 0; nt < 4; ++nt) {
      short8 b0 = *(const short8*)&bs[(nt * 16 + n16) * 64 + ((quad ^ (n16 & 7)) * 8)];
      short8 b1 = *(const short8*)&bs[(nt * 16 + n16) * 64 + (((quad + 4) ^ (n16 & 7)) * 8)];
      acc[nt] = __builtin_amdgcn_mfma_f32_16x16x32_bf16(a0, b0, acc[nt], 0, 0, 0);
      acc[nt] = __builtin_amdgcn_mfma_f32_16x16x32_bf16(a1, b1, acc[nt], 0, 0, 0);
    }
  }
#pragma unroll
  for (int nt = 0; nt < 4; ++nt)
#pragma unroll
    for (int reg = 0; reg < 4; ++reg)
      out[((size_t)b * 512 + 256 + o0 + w * 16 + quad * 4 + reg) * LL + s0 + nt * 16 + n16] =
          acc[nt][reg];
}

extern "C" void kernel_launch(void* const* d_in, const int* in_sizes, int n_in,
                              void* d_out, int out_size, void* d_ws, size_t ws_size,
                              hipStream_t stream) {
  const float* x     = (const float*)d_in[0];
  const float* wqkv  = (const float*)d_in[1];
  const float* wconv = (const float*)d_in[2];
  const float* wout  = (const float*)d_in[3];
  const float* krh   = (const float*)d_in[4];
  const float* krw   = (const float*)d_in[5];
  float* out = (float*)d_out;

  unsigned short* qbf = (unsigned short*)d_ws;
  unsigned short* kbf = qbf + (size_t)NB * 8 * LL * 64;
  unsigned short* vbf = kbf + (size_t)NB * 8 * LL * 64;
  unsigned short* abf = vbf + (size_t)NB * DVC * LL;
  unsigned short* relTh = abf + (size_t)NB * LL * DVC;
  unsigned short* relTw = relTh + 4096;
  unsigned short* xTp = relTw + 4096;
  unsigned short* wtap = xTp + (size_t)NB * XPSTRIDE;
  unsigned short* wqbf = wtap + 589824;
  unsigned short* woutbf = wqbf + 327680;

  prep_all<<<dim3(5056), 256, 0, stream>>>(x, wconv, wqkv, wout, krh, krw,
                                           xTp, wtap, wqbf, woutbf, relTh, relTw);
  qkvconv_mfma<<<dim3(3072), 256, 0, stream>>>(xTp, wqbf, wtap, qbf, kbf, vbf, out);
  attn_kernel<<<dim3(1024), 256, 0, stream>>>(qbf, kbf, vbf, relTh, relTw, abf);
  proj_mfma<<<dim3(512), 256, 0, stream>>>(abf, woutbf, out);
}

// Round 18
// 136.625 us; speedup vs baseline: 1.0192x; 1.0192x over previous
//
#include <hip/hip_runtime.h>
#include <cstddef>
#include <cstdint>

#define NB 8
#define CIN 256
#define LL 1024
#define DKC 512
#define DVC 256
#define XPSTRIDE 295936  // 34*34*256

typedef short short8 __attribute__((ext_vector_type(8)));
typedef float f32x4 __attribute__((ext_vector_type(4)));

typedef __attribute__((address_space(1))) const unsigned int gas_u32;
typedef __attribute__((address_space(3))) unsigned int las_u32;

__device__ __forceinline__ unsigned short f2bf(float f) {
  unsigned int u = __float_as_uint(f);
  u += 0x7fffu + ((u >> 16) & 1u);
  return (unsigned short)(u >> 16);
}
__device__ __forceinline__ float bf2f(unsigned short u) {
  return __uint_as_float(((unsigned int)u) << 16);
}

// ---------------- merged prep: xpad_interior + xpad_border + weight prep --
// blocks [0,128): xpad interior; [128,1184): border zeros; [1184,5056): weights
__global__ __launch_bounds__(256) void prep_all(
    const float* __restrict__ x, const float* __restrict__ wconv,
    const float* __restrict__ wqkv, const float* __restrict__ wout,
    const float* __restrict__ krh, const float* __restrict__ krw,
    unsigned short* __restrict__ xTp, unsigned short* __restrict__ wtap,
    unsigned short* __restrict__ wqbf, unsigned short* __restrict__ woutbf,
    unsigned short* __restrict__ relTh, unsigned short* __restrict__ relTw) {
  __shared__ float tile[64][65];
  const int bx = blockIdx.x;
  const int tid = threadIdx.x;
  if (bx < 128) {
    // ---- xpad interior: x [b][c][1024] fp32 -> xTp [b][34][34][c] bf16
    const int st = bx & 15;
    const int b = bx >> 4;
    const int s0 = st * 64;
    const int h0 = st * 2;
    for (int cc = 0; cc < 4; ++cc) {
      const int c0 = cc * 64;
      {
        const int row = tid >> 2;
        const int j0 = (tid & 3) * 16;
#pragma unroll
        for (int k = 0; k < 4; ++k)
          *(float4*)&tile[row][j0 + k * 4] =
              *(const float4*)(x + ((size_t)(b * CIN + c0 + row)) * LL + s0 + j0 + k * 4);
      }
      __syncthreads();
      {
        const int sl = tid >> 2;
        const int cb = (tid & 3) * 16;
        unsigned short buf[16];
#pragma unroll
        for (int m = 0; m < 16; ++m) buf[m] = f2bf(tile[cb + m][sl]);
        const int hp = h0 + (sl >> 5) + 1;
        const int wp = (sl & 31) + 1;
        unsigned short* dst = xTp + (size_t)b * XPSTRIDE + (hp * 34 + wp) * 256 + c0 + cb;
        *(uint4*)dst = *(uint4*)&buf[0];
        *(uint4*)(dst + 8) = *(uint4*)&buf[8];
      }
      __syncthreads();
    }
  } else if (bx < 1184) {
    // ---- xpad border zeros
    const int idx = (bx - 128) * 256 + tid;
    const int b = idx / 33792;
    const int rem = idx - b * 33792;
    const int pos = rem >> 8, c = rem & 255;
    int hp, wp;
    if (pos < 34) { hp = 0; wp = pos; }
    else if (pos < 68) { hp = 33; wp = pos - 34; }
    else if (pos < 100) { hp = pos - 68 + 1; wp = 0; }
    else { hp = pos - 100 + 1; wp = 33; }
    xTp[(size_t)b * XPSTRIDE + (hp * 34 + wp) * 256 + c] = 0;
  } else {
    // ---- weight/rel prep (fp32 -> bf16, relayout)
    const int idx = (bx - 1184) * 256 + tid;
    if (idx < 589824) {
      const int tap = idx >> 16;
      const int rem = idx & 65535;
      wtap[idx] = f2bf(wconv[(size_t)rem * 9 + tap]);
    } else if (idx < 917504) {
      const int j = idx - 589824;
      const int o = j >> 8;
      const float sc = (o < DKC) ? 0.125f * 1.44269504088896f : 1.0f;
      wqbf[j] = f2bf(wqkv[j] * sc);
    } else if (idx < 983040) {
      const int j = idx - 917504;
      woutbf[j] = f2bf(wout[j]);
    } else {
      const int j = idx - 983040;
      const int tbl = j >> 12;
      const int rest = j & 4095;
      const int m = rest >> 6, c = rest & 63;
      const float* src = tbl ? krw : krh;
      unsigned short* dst = tbl ? relTw : relTh;
      const float v = (m < 63) ? src[c * 63 + m] : 0.f;
      dst[m * 64 + c] = f2bf(v);
    }
  }
}

// ---------------- merged qkv + conv, 1-D grid, XCD-safe role split -------
// lin < 512: conv (long poles, dispatched first); lin >= 512: qkv (2560
// blocks stream-backfill). Role varies along lin/256 -> every CU gets 2
// conv blocks + a stream of qkv blocks (dispatch: block lin -> XCD lin%8).
// BOTH roles stage via global_load_lds with pre-swizzled source
// (r13/r14 pattern): LDS cell [r][g] holds source granule g^(r&7);
// trow = tid>>3 = w*8+(lane>>3), so lane l fetches src+((l&7)^(l>>3))*8,
// dest = linear wave base + lane*16. One barrier per K-iter.
__global__ __launch_bounds__(256) void qkvconv_mfma(
    const unsigned short* __restrict__ xTp, const unsigned short* __restrict__ wqbf,
    const unsigned short* __restrict__ wtap, unsigned short* __restrict__ qbf,
    unsigned short* __restrict__ kbf, unsigned short* __restrict__ vbf,
    float* __restrict__ out) {
  __shared__ __align__(16) char smem[32768];
  const int tid = threadIdx.x;
  const int lane = tid & 63, w = tid >> 6;
  const int n16 = lane & 15, quad = lane >> 4;
  const int lin = blockIdx.x;
  const int trow = tid >> 3;
  const int ck = tid & 7;
  const int lr = lane >> 3;            // 0..7
  const int lg = lane & 7;
  const int gsw = (lg ^ lr) * 8;       // pre-swizzled granule (u16 offset)

  if (lin < 512) {
    // ================= conv (implicit GEMM, BK=64, async dbuf) ==========
    const int ot = lin & 3;
    const int st = (lin >> 2) & 15;
    const int b = lin >> 6;
    const int s0 = st * 64;
    const int h0 = st * 2;
    unsigned short* asb = (unsigned short*)smem;             // 2x[64][64]
    unsigned short* bsb = (unsigned short*)(smem + 16384);   // 2x[64][64]
    const unsigned short* xb = xTp + (size_t)b * XPSTRIDE;
    const unsigned short* wbase = wtap + (size_t)(ot * 64) * 256;

    f32x4 acc[4];
#pragma unroll
    for (int nt = 0; nt < 4; ++nt) acc[nt] = (f32x4){0.f, 0.f, 0.f, 0.f};

    auto issue = [&](int it, int bufi) {
      const int tap = it >> 2;
      const int c0 = (it & 3) * 64;
      const int dh = tap / 3 - 1;
      const int dw = tap - (tap / 3) * 3 - 1;
      const unsigned short* wt = wbase + (size_t)tap * 65536;
      unsigned short* ad = asb + bufi * 4096 + w * 512;
      unsigned short* bd = bsb + bufi * 4096 + w * 512;
      const unsigned short* asrc = wt + (size_t)trow * 256 + c0 + gsw;
      __builtin_amdgcn_global_load_lds((gas_u32*)asrc, (las_u32*)ad, 16, 0, 0);
      __builtin_amdgcn_global_load_lds((gas_u32*)(asrc + 32 * 256), (las_u32*)(ad + 2048), 16, 0, 0);
      const int wp = trow + dw + 1;      // trow 0..31
      const unsigned short* bsrc = xb + (size_t)((h0 + dh + 1) * 34 + wp) * 256 + c0 + gsw;
      __builtin_amdgcn_global_load_lds((gas_u32*)bsrc, (las_u32*)bd, 16, 0, 0);
      __builtin_amdgcn_global_load_lds((gas_u32*)(bsrc + 34 * 256), (las_u32*)(bd + 2048), 16, 0, 0);
    };
    issue(0, 0);
    for (int it = 0; it < 36; ++it) {
      __syncthreads();                  // tile it ready (vmcnt0 drained)
      if (it < 35) issue(it + 1, (it + 1) & 1);  // async into other buffer
      const unsigned short* ab = asb + (it & 1) * 4096;
      const unsigned short* bb = bsb + (it & 1) * 4096;
      short8 a0 = *(const short8*)&ab[(w * 16 + n16) * 64 + ((quad ^ (n16 & 7)) * 8)];
      short8 a1 = *(const short8*)&ab[(w * 16 + n16) * 64 + (((quad + 4) ^ (n16 & 7)) * 8)];
#pragma unroll
      for (int nt = 0; nt < 4; ++nt) {
        short8 b0 = *(const short8*)&bb[(nt * 16 + n16) * 64 + ((quad ^ (n16 & 7)) * 8)];
        short8 b1 = *(const short8*)&bb[(nt * 16 + n16) * 64 + (((quad + 4) ^ (n16 & 7)) * 8)];
        acc[nt] = __builtin_amdgcn_mfma_f32_16x16x32_bf16(a0, b0, acc[nt], 0, 0, 0);
        acc[nt] = __builtin_amdgcn_mfma_f32_16x16x32_bf16(a1, b1, acc[nt], 0, 0, 0);
      }
    }
#pragma unroll
    for (int nt = 0; nt < 4; ++nt)
#pragma unroll
      for (int reg = 0; reg < 4; ++reg)
        out[((size_t)b * 512 + ot * 64 + w * 16 + quad * 4 + reg) * LL + s0 + nt * 16 + n16] =
            acc[nt][reg];
  } else {
    // ================= qkv projection (async dbuf, 1 barrier/iter) ======
    const int l2 = lin - 512;        // 0..2559 = 20*16*8
    const int ot = l2 % 20;
    const int rest = l2 / 20;
    const int st = rest & 15;
    const int b = rest >> 4;
    const int o0 = ot * 64;
    const int s0 = st * 64;
    const int h0 = st * 2;
    unsigned short* asb = (unsigned short*)smem;             // 2x[64][64]
    unsigned short* bsb = (unsigned short*)(smem + 16384);   // 2x[64][64]
    float (*trans)[65] = (float(*)[65])smem;  // overlays after final reads

    const unsigned short* xb = xTp + (size_t)b * XPSTRIDE;
    const unsigned short* wt = wqbf + (size_t)o0 * 256;

    f32x4 acc[4];
#pragma unroll
    for (int nt = 0; nt < 4; ++nt) acc[nt] = (f32x4){0.f, 0.f, 0.f, 0.f};

    auto issue = [&](int kc, int bufi) {
      const int c0 = kc * 64;
      unsigned short* ad = asb + bufi * 4096 + w * 512;
      unsigned short* bd = bsb + bufi * 4096 + w * 512;
      const unsigned short* asrc = wt + (size_t)trow * 256 + c0 + gsw;
      __builtin_amdgcn_global_load_lds((gas_u32*)asrc, (las_u32*)ad, 16, 0, 0);
      __builtin_amdgcn_global_load_lds((gas_u32*)(asrc + 32 * 256), (las_u32*)(ad + 2048), 16, 0, 0);
      const int wpos = trow + 1;         // trow 0..31
      const unsigned short* bsrc = xb + (size_t)((h0 + 1) * 34 + wpos) * 256 + c0 + gsw;
      __builtin_amdgcn_global_load_lds((gas_u32*)bsrc, (las_u32*)bd, 16, 0, 0);
      __builtin_amdgcn_global_load_lds((gas_u32*)(bsrc + 34 * 256), (las_u32*)(bd + 2048), 16, 0, 0);
    };
    issue(0, 0);
#pragma unroll
    for (int kc = 0; kc < 4; ++kc) {
      __syncthreads();                  // tile kc ready (vmcnt0 drained)
      if (kc < 3) issue(kc + 1, (kc + 1) & 1);
      const unsigned short* as = asb + (kc & 1) * 4096;
      const unsigned short* bs = bsb + (kc & 1) * 4096;
      short8 a0 = *(const short8*)&as[(w * 16 + n16) * 64 + ((quad ^ (n16 & 7)) * 8)];
      short8 a1 = *(const short8*)&as[(w * 16 + n16) * 64 + (((quad + 4) ^ (n16 & 7)) * 8)];
#pragma unroll
      for (int nt = 0; nt < 4; ++nt) {
        short8 b0 = *(const short8*)&bs[(nt * 16 + n16) * 64 + ((quad ^ (n16 & 7)) * 8)];
        short8 b1 = *(const short8*)&bs[(nt * 16 + n16) * 64 + (((quad + 4) ^ (n16 & 7)) * 8)];
        acc[nt] = __builtin_amdgcn_mfma_f32_16x16x32_bf16(a0, b0, acc[nt], 0, 0, 0);
        acc[nt] = __builtin_amdgcn_mfma_f32_16x16x32_bf16(a1, b1, acc[nt], 0, 0, 0);
      }
    }
    __syncthreads();
#pragma unroll
    for (int nt = 0; nt < 4; ++nt)
#pragma unroll
      for (int reg = 0; reg < 4; ++reg)
        trans[w * 16 + quad * 4 + reg][nt * 16 + n16] = acc[nt][reg];
    __syncthreads();
    const int sl = tid >> 2;
    const int cseg = (tid & 3) * 16;
    unsigned short buf[16];
    if (ot < 16) {
#pragma unroll
      for (int m = 0; m < 16; ++m) buf[m] = f2bf(trans[cseg + m][sl]);
      unsigned short* dst;
      int head;
      if (ot < 8) { dst = qbf; head = ot; }
      else { dst = kbf; head = ot - 8; }
      const size_t base = (((size_t)(b * 8 + head)) * LL + s0 + sl) * 64 + cseg;
      *(uint4*)(dst + base) = *(uint4*)&buf[0];
      *(uint4*)(dst + base + 8) = *(uint4*)&buf[8];
    } else {
#pragma unroll
      for (int m = 0; m < 16; ++m) buf[m] = f2bf(trans[sl][cseg + m]);
      unsigned short* dst = vbf + ((size_t)b * DVC + (ot - 16) * 64 + sl) * LL + s0 + cseg;
      *(uint4*)dst = *(uint4*)&buf[0];
      *(uint4*)(dst + 8) = *(uint4*)&buf[8];
    }
  }
}

// ---------------- MFMA flash attention: swapped QK^T, in-register P ------
// round-9 structure, K/V staging via global_load_lds (width 16) with
// pre-swizzled global source (r13, verified).
__global__ __launch_bounds__(256, 4) void attn_kernel(
    const unsigned short* __restrict__ qbf, const unsigned short* __restrict__ kbf,
    const unsigned short* __restrict__ vbf, const unsigned short* __restrict__ relTh,
    const unsigned short* __restrict__ relTw, unsigned short* __restrict__ abf) {
  __shared__ __align__(16) char smem[32768];
  unsigned short* ks = (unsigned short*)smem;              // 2x[64][64] swizzled
  unsigned short* vs = (unsigned short*)(smem + 16384);    // 2x[32][64] swizzled
  unsigned short* rwtT = (unsigned short*)(smem + 24576);  // [64 m][64 q] swizzled
  unsigned short* ps = (unsigned short*)(smem + 8192);     // transient rh tile (= ks buf1)
  float* obuf = (float*)smem;                              // [64][33] fp32 overlay

  const int tid = threadIdx.x;
  const int lane = tid & 63, w = tid >> 6;
  const int n16 = lane & 15, quad = lane >> 4;
  const int blk = blockIdx.x;
  const int bn = blk & 63, qb = blk >> 6;
  const int n = bn & 7, b = bn >> 3;
  const int s0 = qb * 64;
  const int aa = 2 * qb + (w >> 1);
  const int pb = (w & 1) * 16;

  const unsigned short* qbase = qbf + ((size_t)(b * 8 + n)) * LL * 64;
  const unsigned short* kbase = kbf + ((size_t)(b * 8 + n)) * LL * 64;
  const unsigned short* vbase = vbf + ((size_t)(b * 8 + n)) * 32 * LL;

  // staging geometry: lane l of wave w fetches row 8w+(l>>3), granule l&7
  const int lr = lane >> 3;                       // 0..7
  const int lg = lane & 7;
  const int wkey = (lr & 3) | ((w & 1) << 2);     // == key(8w+lr) == key(+32)
  const int gsw = (lg ^ wkey) * 8;                // pre-swizzled granule (u16)
  const int krow0 = w * 8 + lr;                   // 0..31
  // read keys (lane-constant): kb rows krb+..., vb rows ct*16+n16
  const int krb = (n16 >> 2) * 8 + (n16 & 3);
  const int kk = (n16 & 3) | (((n16 >> 2) & 1) << 2);
  const int vk = (n16 & 3) | (((n16 >> 3) & 1) << 2);
  const int qcol = w * 16 + n16;

  auto issue_tile = [&](int t0, int bufi) {
    unsigned short* kd = ks + bufi * 4096 + w * 512;
    unsigned short* vd = vs + bufi * 2048 + w * 512;
    const unsigned short* ksrc = kbase + (size_t)(t0 + krow0) * 64 + gsw;
    __builtin_amdgcn_global_load_lds((gas_u32*)ksrc, (las_u32*)kd, 16, 0, 0);
    __builtin_amdgcn_global_load_lds((gas_u32*)(ksrc + 32 * 64), (las_u32*)(kd + 2048), 16, 0, 0);
    __builtin_amdgcn_global_load_lds((gas_u32*)(vbase + (size_t)krow0 * LL + t0 + gsw),
                                     (las_u32*)vd, 16, 0, 0);
  };

  // stage tile 0 into buffer 0 (async; drains at the prologue barrier)
  issue_tile(0, 0);

  // ---- prologue: rel tables via MFMA; rw -> transposed LDS, rh transient --
  {
    const int sT = (pb + n16) * 32 + aa;
    short8 ra0 = *(const short8*)(qbase + (size_t)sT * 64 + quad * 8);
    short8 ra1 = *(const short8*)(qbase + (size_t)sT * 64 + 32 + quad * 8);
#pragma unroll
    for (int tbl = 0; tbl < 2; ++tbl) {
      const unsigned short* rel = tbl ? relTh : relTw;
      f32x4 acc[4];
#pragma unroll
      for (int mt = 0; mt < 4; ++mt) acc[mt] = (f32x4){0.f, 0.f, 0.f, 0.f};
#pragma unroll
      for (int mt = 0; mt < 4; ++mt) {
        short8 b0 = *(const short8*)(rel + (mt * 16 + n16) * 64 + quad * 8);
        short8 b1 = *(const short8*)(rel + (mt * 16 + n16) * 64 + 32 + quad * 8);
        acc[mt] = __builtin_amdgcn_mfma_f32_16x16x32_bf16(ra0, b0, acc[mt], 0, 0, 0);
        acc[mt] = __builtin_amdgcn_mfma_f32_16x16x32_bf16(ra1, b1, acc[mt], 0, 0, 0);
      }
      if (tbl == 0) {
#pragma unroll
        for (int mt = 0; mt < 4; ++mt)
#pragma unroll
          for (int reg = 0; reg < 4; ++reg)
            rwtT[(mt * 16 + n16) * 64 +
                 ((w * 16 + quad * 4 + reg) ^ ((n16 & 7) * 8))] = f2bf(acc[mt][reg]);
      } else {
#pragma unroll
        for (int mt = 0; mt < 4; ++mt)
#pragma unroll
          for (int reg = 0; reg < 4; ++reg)
            ps[(w * 16 + quad * 4 + reg) * 64 + mt * 16 + n16] = f2bf(acc[mt][reg]);
      }
    }
  }
  short8 qf0 = *(const short8*)(qbase + (size_t)(s0 + w * 16 + n16) * 64 + quad * 8);
  short8 qf1 = *(const short8*)(qbase + (size_t)(s0 + w * 16 + n16) * 64 + 32 + quad * 8);
  __syncthreads();  // tile-0 loads drained (vmcnt0); rel tables visible
  // hoist rh bias into 8 regs: q = qcol, k%32 = quad*8 + c1*4 + reg
  float rhreg[2][4];
#pragma unroll
  for (int c1 = 0; c1 < 2; ++c1)
#pragma unroll
    for (int reg = 0; reg < 4; ++reg)
      rhreg[c1][reg] =
          bf2f(ps[qcol * 64 + quad * 8 + c1 * 4 + reg + 31 - pb - n16]);
  __syncthreads();  // ps (= ks buf1) reads done before iter0 loads buf1

  float lacc[4] = {0.f, 0.f, 0.f, 0.f};
  f32x4 oacc[2];
  oacc[0] = (f32x4){0.f, 0.f, 0.f, 0.f};
  oacc[1] = (f32x4){0.f, 0.f, 0.f, 0.f};

  int cur = 0;
  for (int kt64 = 0; kt64 < 16; ++kt64) {
    const int t0 = kt64 * 64;
    __syncthreads();  // buf[cur] ready; all waves done reading buf[cur^1]
    if (kt64 < 15) issue_tile(t0 + 64, cur ^ 1);  // async into the other buffer
    const unsigned short* ksb = ks + cur * 4096;
    const unsigned short* vsb = vs + cur * 2048;

    // swapped QK^T with permuted K rows: sacc[c][reg] =
    //   S[q=qcol][k = t0 + (c>>1)*32 + (c&1)*4 + quad*8 + reg]
    f32x4 sacc[4];
#pragma unroll
    for (int c = 0; c < 4; ++c) sacc[c] = (f32x4){0.f, 0.f, 0.f, 0.f};
#pragma unroll
    for (int c = 0; c < 4; ++c) {
      const int ro = (krb + (c & 1) * 4 + (c >> 1) * 32) * 64;
      short8 kb0 = *(const short8*)&ksb[ro + ((quad ^ kk) * 8)];
      short8 kb1 = *(const short8*)&ksb[ro + (((quad + 4) ^ kk) * 8)];
      sacc[c] = __builtin_amdgcn_mfma_f32_16x16x32_bf16(kb0, qf0, sacc[c], 0, 0, 0);
      sacc[c] = __builtin_amdgcn_mfma_f32_16x16x32_bf16(kb1, qf1, sacc[c], 0, 0, 0);
    }
    // rw bias: one u16 per 32-k half for this lane's q row
    float rww[2];
#pragma unroll
    for (int h = 0; h < 2; ++h) {
      const int mw = (t0 >> 5) + h - aa + 31;
      rww[h] = bf2f(rwtT[mw * 64 + (qcol ^ ((mw & 7) * 8))]);
    }
    // P = exp2(s + rw + rh), packed to bf16 pairs entirely in-register
    unsigned int pkw[2][4];
#pragma unroll
    for (int c = 0; c < 4; ++c) {
      float e[4];
#pragma unroll
      for (int reg = 0; reg < 4; ++reg) {
        e[reg] = __builtin_amdgcn_exp2f(sacc[c][reg] + rww[c >> 1] + rhreg[c & 1][reg]);
        lacc[reg] += e[reg];
      }
      unsigned int p0, p1;
      asm("v_cvt_pk_bf16_f32 %0, %1, %2" : "=v"(p0) : "v"(e[0]), "v"(e[1]));
      asm("v_cvt_pk_bf16_f32 %0, %1, %2" : "=v"(p1) : "v"(e[2]), "v"(e[3]));
      pkw[c >> 1][(c & 1) * 2] = p0;
      pkw[c >> 1][(c & 1) * 2 + 1] = p1;
    }
    // PV: pa is lane-local A-fragment, V from LDS
#pragma unroll
    for (int kt = 0; kt < 2; ++kt) {
      uint4 pw;
      pw.x = pkw[kt][0]; pw.y = pkw[kt][1]; pw.z = pkw[kt][2]; pw.w = pkw[kt][3];
      short8 pa = *(short8*)&pw;
#pragma unroll
      for (int ct = 0; ct < 2; ++ct) {
        short8 vb = *(const short8*)&vsb[(ct * 16 + n16) * 64 + (((quad + 4 * kt) ^ vk) * 8)];
        oacc[ct] = __builtin_amdgcn_mfma_f32_16x16x32_bf16(pa, vb, oacc[ct], 0, 0, 0);
      }
    }
    cur ^= 1;
  }
  // row-sum: lane holds partial for q=qcol; reduce across quads, then
  // redistribute 1/l to the O layout rows (quad*4+reg)
  float lsum = (lacc[0] + lacc[1]) + (lacc[2] + lacc[3]);
  lsum += __shfl_xor(lsum, 16);
  lsum += __shfl_xor(lsum, 32);
  const float linv_own = 1.0f / lsum;
  float linv[4];
#pragma unroll
  for (int reg = 0; reg < 4; ++reg)
    linv[reg] = __shfl(linv_own, (lane & 48) | (quad * 4 + reg));
  __syncthreads();
#pragma unroll
  for (int ct = 0; ct < 2; ++ct)
#pragma unroll
    for (int reg = 0; reg < 4; ++reg)
      obuf[(w * 16 + quad * 4 + reg) * 33 + ct * 16 + n16] = oacc[ct][reg] * linv[reg];
  __syncthreads();
  {
    const int row = tid >> 2;
    const int cseg = (tid & 3) * 8;
    unsigned short buf8[8];
#pragma unroll
    for (int m = 0; m < 8; ++m) buf8[m] = f2bf(obuf[row * 33 + cseg + m]);
    *(uint4*)(abf + (((size_t)b * LL) + s0 + row) * 256 + n * 32 + cseg) = *(uint4*)&buf8[0];
  }
}

// ---------------- output projection as bf16 MFMA GEMM (standalone) -------
__global__ __launch_bounds__(256) void proj_mfma(
    const unsigned short* __restrict__ abf, const unsigned short* __restrict__ woutbf,
    float* __restrict__ out) {
  __shared__ __align__(16) unsigned short as[64 * 64];
  __shared__ __align__(16) unsigned short bs[64 * 64];
  const int tid = threadIdx.x;
  const int lane = tid & 63, w = tid >> 6;
  const int n16 = lane & 15, quad = lane >> 4;
  const int ot = blockIdx.x;
  const int st = blockIdx.y;
  const int b = blockIdx.z;
  const int o0 = ot * 64;
  const int s0 = st * 64;
  const int trow = tid >> 3, ck = tid & 7;

  const unsigned short* ab = abf + ((size_t)b * LL + s0) * 256;
  const unsigned short* wt = woutbf + (size_t)o0 * 256;

  f32x4 acc[4];
#pragma unroll
  for (int nt = 0; nt < 4; ++nt) acc[nt] = (f32x4){0.f, 0.f, 0.f, 0.f};

  uint4 ra0, ra1, rb0, rb1;
  ra0 = *(const uint4*)(wt + (size_t)trow * 256 + ck * 8);
  ra1 = *(const uint4*)(wt + (size_t)(trow + 32) * 256 + ck * 8);
  rb0 = *(const uint4*)(ab + (size_t)trow * 256 + ck * 8);
  rb1 = *(const uint4*)(ab + (size_t)(trow + 32) * 256 + ck * 8);
#pragma unroll
  for (int kc = 0; kc < 4; ++kc) {
    __syncthreads();
    *(uint4*)&as[trow * 64 + ((ck ^ (trow & 7)) * 8)] = ra0;
    *(uint4*)&as[(trow + 32) * 64 + ((ck ^ (trow & 7)) * 8)] = ra1;
    *(uint4*)&bs[trow * 64 + ((ck ^ (trow & 7)) * 8)] = rb0;
    *(uint4*)&bs[(trow + 32) * 64 + ((ck ^ (trow & 7)) * 8)] = rb1;
    __syncthreads();
    if (kc < 3) {
      const int c0 = (kc + 1) * 64;
      ra0 = *(const uint4*)(wt + (size_t)trow * 256 + c0 + ck * 8);
      ra1 = *(const uint4*)(wt + (size_t)(trow + 32) * 256 + c0 + ck * 8);
      rb0 = *(const uint4*)(ab + (size_t)trow * 256 + c0 + ck * 8);
      rb1 = *(const uint4*)(ab + (size_t)(trow + 32) * 256 + c0 + ck * 8);
    }
    short8 a0 = *(const short8*)&as[(w * 16 + n16) * 64 + ((quad ^ (n16 & 7)) * 8)];
    short8 a1 = *(const short8*)&as[(w * 16 + n16) * 64 + (((quad + 4) ^ (n16 & 7)) * 8)];
#pragma unroll
    for (int nt = 0; nt < 4; ++nt) {
      short8 b0 = *(const short8*)&bs[(nt * 16 + n16) * 64 + ((quad ^ (n16 & 7)) * 8)];
      short8 b1 = *(const short8*)&bs[(nt * 16 + n16) * 64 + (((quad + 4) ^ (n16 & 7)) * 8)];
      acc[nt] = __builtin_amdgcn_mfma_f32_16x16x32_bf16(a0, b0, acc[nt], 0, 0, 0);
      acc[nt] = __builtin_amdgcn_mfma_f32_16x16x32_bf16(a1, b1, acc[nt], 0, 0, 0);
    }
  }
#pragma unroll
  for (int nt = 0; nt < 4; ++nt)
#pragma unroll
    for (int reg = 0; reg < 4; ++reg)
      out[((size_t)b * 512 + 256 + o0 + w * 16 + quad * 4 + reg) * LL + s0 + nt * 16 + n16] =
          acc[nt][reg];
}

extern "C" void kernel_launch(void* const* d_in, const int* in_sizes, int n_in,
                              void* d_out, int out_size, void* d_ws, size_t ws_size,
                              hipStream_t stream) {
  const float* x     = (const float*)d_in[0];
  const float* wqkv  = (const float*)d_in[1];
  const float* wconv = (const float*)d_in[2];
  const float* wout  = (const float*)d_in[3];
  const float* krh   = (const float*)d_in[4];
  const float* krw   = (const float*)d_in[5];
  float* out = (float*)d_out;

  unsigned short* qbf = (unsigned short*)d_ws;
  unsigned short* kbf = qbf + (size_t)NB * 8 * LL * 64;
  unsigned short* vbf = kbf + (size_t)NB * 8 * LL * 64;
  unsigned short* abf = vbf + (size_t)NB * DVC * LL;
  unsigned short* relTh = abf + (size_t)NB * LL * DVC;
  unsigned short* relTw = relTh + 4096;
  unsigned short* xTp = relTw + 4096;
  unsigned short* wtap = xTp + (size_t)NB * XPSTRIDE;
  unsigned short* wqbf = wtap + 589824;
  unsigned short* woutbf = wqbf + 327680;

  prep_all<<<dim3(5056), 256, 0, stream>>>(x, wconv, wqkv, wout, krh, krw,
                                           xTp, wtap, wqbf, woutbf, relTh, relTw);
  qkvconv_mfma<<<dim3(3072), 256, 0, stream>>>(xTp, wqbf, wtap, qbf, kbf, vbf, out);
  attn_kernel<<<dim3(1024), 256, 0, stream>>>(qbf, kbf, vbf, relTh, relTw, abf);
  proj_mfma<<<dim3(4, 16, NB), 256, 0, stream>>>(abf, woutbf, out);
}